// Round 1
// baseline (44.794 us; speedup 1.0000x reference)
//
#include <hip/hip_runtime.h>

#define EPS 1e-5f

static __device__ const int OFFS[8] = {0, 100000, 150000, 151000, 151500, 151600, 151650, 151670};

// K1: per 16 rows/block: gather embeddings -> FM terms -> h0 (LDS) -> z1 = h0@W1+b1
// plus per-block column {sum, sumsq} partials of z1.
__global__ __launch_bounds__(256) void k1_gather_fm_gemm1(
    const int* __restrict__ x, const float* __restrict__ emb,
    const float* __restrict__ wlin, const float* __restrict__ blin,
    const float* __restrict__ W1, const float* __restrict__ b1,
    float* __restrict__ yfm, float* __restrict__ z1, float* __restrict__ p1)
{
    __shared__ float h0s[16][128];
    const int t = threadIdx.x;
    const int blk = blockIdx.x;
    const int r = t >> 4, l = t & 15;
    const int b = blk * 16 + r;

    int idx[8];
#pragma unroll
    for (int f = 0; f < 8; ++f) idx[f] = x[b * 8 + f];

    float s = 0.f, ssq = 0.f;
#pragma unroll
    for (int f = 0; f < 8; ++f) {
        float e = emb[(idx[f] + OFFS[f]) * 16 + l];
        h0s[r][f * 16 + l] = e;
        s += e;
        ssq += e * e;
    }
    float pair = s * s - ssq;   // per-dim contribution
#pragma unroll
    for (int m = 8; m >= 1; m >>= 1) pair += __shfl_xor(pair, m);  // reduce over 16 dims

    if (l == 0) {
        // linear term: reference one-hot uses .set(1.0) on RAW indices -> dedupe duplicates
        float lin = 0.f;
#pragma unroll
        for (int f = 0; f < 8; ++f) {
            bool dup = false;
            for (int g = 0; g < f; ++g) dup = dup || (idx[g] == idx[f]);
            if (!dup) lin += wlin[idx[f]];
        }
        yfm[b] = 0.5f * pair + lin + blin[0];
    }
    __syncthreads();

    // GEMM1: thread j computes column j for all 16 rows
    const int j = t;
    float acc[16];
#pragma unroll
    for (int r2 = 0; r2 < 16; ++r2) acc[r2] = 0.f;
    for (int k = 0; k < 128; ++k) {
        float w = W1[k * 256 + j];
#pragma unroll
        for (int r2 = 0; r2 < 16; ++r2) acc[r2] += h0s[r2][k] * w;
    }
    const float bj = b1[j];
    float zsum = 0.f, zss = 0.f;
#pragma unroll
    for (int r2 = 0; r2 < 16; ++r2) {
        float z = acc[r2] + bj;
        z1[(blk * 16 + r2) * 256 + j] = z;
        zsum += z;
        zss += z * z;
    }
    p1[blk * 512 + j] = zsum;
    p1[blk * 512 + 256 + j] = zss;
}

// K2: reduce BN1 stats (redundantly per block, deterministic), h1=relu(bn(z1)),
// z2 = h1@W2+b2, per-block column partials of z2. 32 rows/block.
__global__ __launch_bounds__(256) void k2_bn1_gemm2(
    const float* __restrict__ z1, const float* __restrict__ p1,
    const float* __restrict__ g1, const float* __restrict__ be1,
    const float* __restrict__ W2, const float* __restrict__ b2,
    float* __restrict__ z2, float* __restrict__ p2)
{
    __shared__ float h1s[32][256];
    __shared__ float psum[2][128];
    __shared__ float pss[2][128];
    const int t = threadIdx.x, blk = blockIdx.x;

    // BN1 stats for column t
    float sum = 0.f, ss = 0.f;
    for (int q = 0; q < 128; ++q) {
        sum += p1[q * 512 + t];
        ss  += p1[q * 512 + 256 + t];
    }
    const float mean = sum * (1.f / 2048.f);
    const float var  = ss * (1.f / 2048.f) - mean * mean;
    const float scale = g1[t] / sqrtf(var + EPS);
    const float shift = be1[t] - mean * scale;

    for (int r = 0; r < 32; ++r) {
        float z = z1[(blk * 32 + r) * 256 + t];
        float h = z * scale + shift;
        h1s[r][t] = h > 0.f ? h : 0.f;
    }
    __syncthreads();

    // GEMM2: col j, half of the 32 rows per thread
    const int j = t & 127, half = t >> 7;
    float acc[16];
#pragma unroll
    for (int r = 0; r < 16; ++r) acc[r] = 0.f;
    for (int k = 0; k < 256; ++k) {
        float w = W2[k * 128 + j];
#pragma unroll
        for (int r = 0; r < 16; ++r) acc[r] += h1s[half * 16 + r][k] * w;
    }
    const float bj = b2[j];
    float zsum = 0.f, zss = 0.f;
#pragma unroll
    for (int r = 0; r < 16; ++r) {
        float z = acc[r] + bj;
        z2[(blk * 32 + half * 16 + r) * 128 + j] = z;
        zsum += z;
        zss += z * z;
    }
    psum[half][j] = zsum;
    pss[half][j] = zss;
    __syncthreads();
    if (half == 0) {
        p2[blk * 256 + j]       = psum[0][j] + psum[1][j];
        p2[blk * 256 + 128 + j] = pss[0][j] + pss[1][j];
    }
}

// K3: BN2 stats, h2=relu(bn(z2)), y = h2@W3 + b3 + y_fm. 32 rows/block, 8 threads/row.
__global__ __launch_bounds__(256) void k3_bn2_out(
    const float* __restrict__ z2, const float* __restrict__ p2,
    const float* __restrict__ g2, const float* __restrict__ be2,
    const float* __restrict__ W3, const float* __restrict__ b3,
    const float* __restrict__ yfm, float* __restrict__ out)
{
    __shared__ float scl[128], shf[128];
    const int t = threadIdx.x, blk = blockIdx.x;
    if (t < 128) {
        float sum = 0.f, ss = 0.f;
        for (int q = 0; q < 64; ++q) {
            sum += p2[q * 256 + t];
            ss  += p2[q * 256 + 128 + t];
        }
        const float mean = sum * (1.f / 2048.f);
        const float var  = ss * (1.f / 2048.f) - mean * mean;
        const float sc = g2[t] / sqrtf(var + EPS);
        scl[t] = sc;
        shf[t] = be2[t] - mean * sc;
    }
    __syncthreads();

    const int r = t >> 3, l8 = t & 7;
    const int b = blk * 32 + r;
    float acc = 0.f;
#pragma unroll
    for (int q = 0; q < 16; ++q) {
        int k = q * 8 + l8;
        float z = z2[b * 128 + k];
        float h = z * scl[k] + shf[k];
        h = h > 0.f ? h : 0.f;
        acc += h * W3[k];
    }
#pragma unroll
    for (int m = 4; m >= 1; m >>= 1) acc += __shfl_xor(acc, m);
    if (l8 == 0) out[b] = acc + b3[0] + yfm[b];
}

extern "C" void kernel_launch(void* const* d_in, const int* in_sizes, int n_in,
                              void* d_out, int out_size, void* d_ws, size_t ws_size,
                              hipStream_t stream) {
    const int*   x    = (const int*)d_in[0];
    const float* emb  = (const float*)d_in[1];
    const float* wlin = (const float*)d_in[2];
    const float* blin = (const float*)d_in[3];
    const float* W1   = (const float*)d_in[4];
    const float* b1   = (const float*)d_in[5];
    const float* g1   = (const float*)d_in[6];
    const float* be1  = (const float*)d_in[7];
    const float* W2   = (const float*)d_in[8];
    const float* b2   = (const float*)d_in[9];
    const float* g2   = (const float*)d_in[10];
    const float* be2  = (const float*)d_in[11];
    const float* W3   = (const float*)d_in[12];
    const float* b3   = (const float*)d_in[13];

    float* ws  = (float*)d_ws;
    float* yfm = ws;                 // 2048
    float* z1  = yfm + 2048;         // 2048*256
    float* p1  = z1 + 2048 * 256;    // 128*512
    float* z2  = p1 + 128 * 512;     // 2048*128
    float* p2  = z2 + 2048 * 128;    // 64*256
    float* out = (float*)d_out;

    k1_gather_fm_gemm1<<<128, 256, 0, stream>>>(x, emb, wlin, blin, W1, b1, yfm, z1, p1);
    k2_bn1_gemm2<<<64, 256, 0, stream>>>(z1, p1, g1, be1, W2, b2, z2, p2);
    k3_bn2_out<<<64, 256, 0, stream>>>(z2, p2, g2, be2, W3, b3, yfm, out);
}

// Round 2
// 37.839 us; speedup vs baseline: 1.1838x; 1.1838x over previous
//
#include <hip/hip_runtime.h>

#define EPS 1e-5f

static __device__ const int OFFS[8] = {0, 100000, 150000, 151000, 151500, 151600, 151650, 151670};

// K1: 256 blocks = 128 row-tiles (16 rows) x 2 col-halves (128 cols of 256).
// gather -> FM (ch==0 only) -> h0 in LDS -> GEMM1 tile -> z1 + per-block col partials.
__global__ __launch_bounds__(256) void k1_gather_fm_gemm1(
    const int* __restrict__ x, const float* __restrict__ emb,
    const float* __restrict__ wlin, const float* __restrict__ blin,
    const float* __restrict__ W1, const float* __restrict__ b1,
    float* __restrict__ yfm, float* __restrict__ z1, float* __restrict__ p1)
{
    __shared__ __align__(16) float h0s[16][128];
    __shared__ __align__(16) float red[2][8][128];
    const int t = threadIdx.x;
    const int rt = blockIdx.x >> 1;      // row tile
    const int ch = blockIdx.x & 1;       // col half

    // ---- gather: thread (g_r, g_l) loads dim g_l of each field for row g_r
    {
        const int g_r = t >> 4, g_l = t & 15;
        const int b = rt * 16 + g_r;
        int idx[8];
#pragma unroll
        for (int f = 0; f < 8; ++f) idx[f] = x[b * 8 + f];

        float s = 0.f, ssq = 0.f;
#pragma unroll
        for (int f = 0; f < 8; ++f) {
            float e = emb[(idx[f] + OFFS[f]) * 16 + g_l];
            h0s[g_r][f * 16 + g_l] = e;
            s += e;
            ssq += e * e;
        }
        if (ch == 0) {
            float pair = s * s - ssq;
#pragma unroll
            for (int m = 8; m >= 1; m >>= 1) pair += __shfl_xor(pair, m);
            if (g_l == 0) {
                float lin = 0.f;
#pragma unroll
                for (int f = 0; f < 8; ++f) {
                    bool dup = false;
                    for (int g = 0; g < f; ++g) dup = dup || (idx[g] == idx[f]);
                    if (!dup) lin += wlin[idx[f]];
                }
                yfm[b] = 0.5f * pair + lin + blin[0];
            }
        }
    }
    __syncthreads();

    // ---- GEMM1: thread = (rp = t>>5 row-pair, jg = t&31 col-group of 4)
    const int jg = t & 31, rp = t >> 5;
    const float* Wb = W1 + ch * 128 + jg * 4;
    float acc0[4] = {0.f, 0.f, 0.f, 0.f};
    float acc1[4] = {0.f, 0.f, 0.f, 0.f};
    for (int k = 0; k < 128; k += 4) {
        float4 ha = *(const float4*)&h0s[rp * 2][k];
        float4 hb = *(const float4*)&h0s[rp * 2 + 1][k];
        const float ha_[4] = {ha.x, ha.y, ha.z, ha.w};
        const float hb_[4] = {hb.x, hb.y, hb.z, hb.w};
#pragma unroll
        for (int kk = 0; kk < 4; ++kk) {
            float4 w = *(const float4*)&Wb[(k + kk) * 256];
            acc0[0] += ha_[kk] * w.x; acc0[1] += ha_[kk] * w.y;
            acc0[2] += ha_[kk] * w.z; acc0[3] += ha_[kk] * w.w;
            acc1[0] += hb_[kk] * w.x; acc1[1] += hb_[kk] * w.y;
            acc1[2] += hb_[kk] * w.z; acc1[3] += hb_[kk] * w.w;
        }
    }
    float4 bj = *(const float4*)&b1[ch * 128 + jg * 4];
    const float bj_[4] = {bj.x, bj.y, bj.z, bj.w};
    float zs[4], zss[4];
    float z0[4], z1v[4];
#pragma unroll
    for (int c = 0; c < 4; ++c) {
        z0[c] = acc0[c] + bj_[c];
        z1v[c] = acc1[c] + bj_[c];
        zs[c] = z0[c] + z1v[c];
        zss[c] = z0[c] * z0[c] + z1v[c] * z1v[c];
    }
    const int r0 = rt * 16 + rp * 2;
    *(float4*)&z1[r0 * 256 + ch * 128 + jg * 4] = make_float4(z0[0], z0[1], z0[2], z0[3]);
    *(float4*)&z1[(r0 + 1) * 256 + ch * 128 + jg * 4] = make_float4(z1v[0], z1v[1], z1v[2], z1v[3]);
    *(float4*)&red[0][rp][jg * 4] = make_float4(zs[0], zs[1], zs[2], zs[3]);
    *(float4*)&red[1][rp][jg * 4] = make_float4(zss[0], zss[1], zss[2], zss[3]);
    __syncthreads();
    if (t < 128) {
        float s = 0.f, ss = 0.f;
#pragma unroll
        for (int q = 0; q < 8; ++q) { s += red[0][q][t]; ss += red[1][q][t]; }
        p1[rt * 512 + ch * 128 + t] = s;
        p1[rt * 512 + 256 + ch * 128 + t] = ss;
    }
}

// K2: 256 blocks x 512 threads; 8 rows each. BN1 stats -> h1 (LDS) -> GEMM2 -> z2 + partials.
__global__ __launch_bounds__(512) void k2_bn1_gemm2(
    const float* __restrict__ z1, const float* __restrict__ p1,
    const float* __restrict__ g1, const float* __restrict__ be1,
    const float* __restrict__ W2, const float* __restrict__ b2,
    float* __restrict__ z2, float* __restrict__ p2)
{
    __shared__ __align__(16) float h1s[8][256];
    __shared__ __align__(16) float sclS[256], shfS[256];
    __shared__ __align__(16) float sp[2][256], ssp[2][256];
    __shared__ __align__(16) float red2[2][8][128];
    const int t = threadIdx.x, rb = blockIdx.x;

    // ---- BN1 stats: 2 threads per column, 64 row-tiles each
    {
        const int col = t & 255, h = t >> 8;
        float s = 0.f, ss = 0.f;
#pragma unroll 16
        for (int q = h * 64; q < h * 64 + 64; ++q) {
            s += p1[q * 512 + col];
            ss += p1[q * 512 + 256 + col];
        }
        sp[h][col] = s; ssp[h][col] = ss;
    }
    __syncthreads();
    if (t < 256) {
        float s = sp[0][t] + sp[1][t];
        float ss = ssp[0][t] + ssp[1][t];
        float mean = s * (1.f / 2048.f);
        float var = ss * (1.f / 2048.f) - mean * mean;
        float sc = g1[t] * __frsqrt_rn(var + EPS);
        sclS[t] = sc;
        shfS[t] = be1[t] - mean * sc;
    }
    __syncthreads();

    // ---- load z1 rows, apply BN+ReLU -> h1s
    {
        const int lr = t >> 6, lc = (t & 63) * 4;
        float4 zv = *(const float4*)&z1[(rb * 8 + lr) * 256 + lc];
        float4 sc = *(const float4*)&sclS[lc];
        float4 sh = *(const float4*)&shfS[lc];
        float4 hv;
        hv.x = fmaxf(zv.x * sc.x + sh.x, 0.f);
        hv.y = fmaxf(zv.y * sc.y + sh.y, 0.f);
        hv.z = fmaxf(zv.z * sc.z + sh.z, 0.f);
        hv.w = fmaxf(zv.w * sc.w + sh.w, 0.f);
        *(float4*)&h1s[lr][lc] = hv;
    }
    __syncthreads();

    // ---- GEMM2: thread = (r = t>>6, j2 = (t&63)*2): 1 row x 2 cols
    const int r = t >> 6, j2 = (t & 63) * 2;
    float acc[2] = {0.f, 0.f};
    for (int k = 0; k < 256; k += 4) {
        float4 hv = *(const float4*)&h1s[r][k];
        const float h_[4] = {hv.x, hv.y, hv.z, hv.w};
#pragma unroll
        for (int kk = 0; kk < 4; ++kk) {
            float2 w = *(const float2*)&W2[(k + kk) * 128 + j2];
            acc[0] += h_[kk] * w.x;
            acc[1] += h_[kk] * w.y;
        }
    }
    float2 bj = *(const float2*)&b2[j2];
    float za = acc[0] + bj.x, zb = acc[1] + bj.y;
    *(float2*)&z2[(rb * 8 + r) * 128 + j2] = make_float2(za, zb);
    *(float2*)&red2[0][r][j2] = make_float2(za, zb);
    *(float2*)&red2[1][r][j2] = make_float2(za * za, zb * zb);
    __syncthreads();
    if (t < 128) {
        float s = 0.f, ss = 0.f;
#pragma unroll
        for (int q = 0; q < 8; ++q) { s += red2[0][q][t]; ss += red2[1][q][t]; }
        p2[rb * 256 + t] = s;
        p2[rb * 256 + 128 + t] = ss;
    }
}

// K3: 256 blocks x 256 threads; 8 rows each. BN2 stats -> relu -> dot W3 -> out.
__global__ __launch_bounds__(256) void k3_bn2_out(
    const float* __restrict__ z2, const float* __restrict__ p2,
    const float* __restrict__ g2, const float* __restrict__ be2,
    const float* __restrict__ W3, const float* __restrict__ b3,
    const float* __restrict__ yfm, float* __restrict__ out)
{
    __shared__ __align__(16) float sp[2][128], ssp[2][128];
    __shared__ __align__(16) float scl[128], shf[128];
    const int t = threadIdx.x, blk = blockIdx.x;
    {
        const int col = t & 127, h = t >> 7;
        float s = 0.f, ss = 0.f;
#pragma unroll 16
        for (int q = h * 128; q < h * 128 + 128; ++q) {
            s += p2[q * 256 + col];
            ss += p2[q * 256 + 128 + col];
        }
        sp[h][col] = s; ssp[h][col] = ss;
    }
    __syncthreads();
    if (t < 128) {
        float s = sp[0][t] + sp[1][t];
        float ss = ssp[0][t] + ssp[1][t];
        float mean = s * (1.f / 2048.f);
        float var = ss * (1.f / 2048.f) - mean * mean;
        float sc = g2[t] * __frsqrt_rn(var + EPS);
        scl[t] = sc;
        shf[t] = be2[t] - mean * sc;
    }
    __syncthreads();

    const int r = t >> 5, l32 = t & 31;
    const int b = blk * 8 + r;
    float4 zv = *(const float4*)&z2[b * 128 + l32 * 4];
    float4 sc = *(const float4*)&scl[l32 * 4];
    float4 sh = *(const float4*)&shf[l32 * 4];
    float4 wv = *(const float4*)&W3[l32 * 4];
    float acc = fmaxf(zv.x * sc.x + sh.x, 0.f) * wv.x
              + fmaxf(zv.y * sc.y + sh.y, 0.f) * wv.y
              + fmaxf(zv.z * sc.z + sh.z, 0.f) * wv.z
              + fmaxf(zv.w * sc.w + sh.w, 0.f) * wv.w;
#pragma unroll
    for (int m = 16; m >= 1; m >>= 1) acc += __shfl_xor(acc, m);
    if (l32 == 0) out[b] = acc + b3[0] + yfm[b];
}

extern "C" void kernel_launch(void* const* d_in, const int* in_sizes, int n_in,
                              void* d_out, int out_size, void* d_ws, size_t ws_size,
                              hipStream_t stream) {
    const int*   x    = (const int*)d_in[0];
    const float* emb  = (const float*)d_in[1];
    const float* wlin = (const float*)d_in[2];
    const float* blin = (const float*)d_in[3];
    const float* W1   = (const float*)d_in[4];
    const float* b1   = (const float*)d_in[5];
    const float* g1   = (const float*)d_in[6];
    const float* be1  = (const float*)d_in[7];
    const float* W2   = (const float*)d_in[8];
    const float* b2   = (const float*)d_in[9];
    const float* g2   = (const float*)d_in[10];
    const float* be2  = (const float*)d_in[11];
    const float* W3   = (const float*)d_in[12];
    const float* b3   = (const float*)d_in[13];

    float* ws  = (float*)d_ws;
    float* yfm = ws;                 // 2048
    float* z1  = yfm + 2048;         // 2048*256
    float* p1  = z1 + 2048 * 256;    // 128*512
    float* z2  = p1 + 128 * 512;     // 2048*128
    float* p2  = z2 + 2048 * 128;    // 256*256
    float* out = (float*)d_out;

    k1_gather_fm_gemm1<<<256, 256, 0, stream>>>(x, emb, wlin, blin, W1, b1, yfm, z1, p1);
    k2_bn1_gemm2<<<256, 512, 0, stream>>>(z1, p1, g1, be1, W2, b2, z2, p2);
    k3_bn2_out<<<256, 256, 0, stream>>>(z2, p2, g2, be2, W3, b3, yfm, out);
}